// Round 7
// baseline (118.761 us; speedup 1.0000x reference)
//
#include <hip/hip_runtime.h>

#define TPTS 100   // points per voxel (T)
#define CO   64    // output channels
#define KK   8     // k-NN

// Distances: the 9-dim edge feature is an affine image of the raw point
// (x,y,z,w), so |f_t - f_s|^2 = 3dx^2 + 3dy^2 + 2dz^2 + dw^2 for valid
// rows; masked columns (f_s = 0) give e = |f_t|^2 (9-dim norm, s_xx).
// Top-8 via packed keys: (as_uint(e) & ~0x7F) | s -- uint order == float
// order (e >= 0), ties break by lowest index.
// R7: in-wave pair split (row = wv*32+(lane&31), side = lane>>5; merge by
// __shfl_xor 32) -> dense wave packing, no LDS key round-trip; s_idx packed
// to 8x8-bit -> LDS = 32768 B exactly = 5 blocks/CU.
__device__ __forceinline__ unsigned umin_(unsigned a, unsigned b) { return a < b ? a : b; }
__device__ __forceinline__ unsigned umax_(unsigned a, unsigned b) { return a > b ? a : b; }

__device__ __forceinline__ unsigned dist_key(const float4 qt, const float4 qs, unsigned s) {
    float dx = qt.x - qs.x, dy = qt.y - qs.y;
    float dz = qt.z - qs.z, dw = qt.w - qs.w;
    float e = __fmaf_rn(dx, dx, __fmaf_rn(dy, dy, __fmaf_rn(dz, dz, dw * dw)));
    return (__float_as_uint(e) & 0xFFFFFF80u) | s;
}

// insert key into sorted-ascending val[0..7]; slots independent (depth 2)
__device__ __forceinline__ void ins8(unsigned val[KK], unsigned key) {
    #pragma unroll
    for (int k = KK - 1; k >= 1; --k)
        val[k] = umin_(val[k], umax_(val[k - 1], key));
    val[0] = umin_(val[0], key);
}

__global__ __launch_bounds__(256) void dgcnn_kernel(
    const float* __restrict__ features,   // [V][100][4]
    const float* __restrict__ conv_w,     // [64][18]
    const float* __restrict__ bn_gamma,
    const float* __restrict__ bn_beta,
    const float* __restrict__ bn_mean,
    const float* __restrict__ bn_var,
    const int*  __restrict__ num_voxels,  // [V]
    const int*  __restrict__ coors,       // [V][4]
    float* __restrict__ out)              // [V][64]
{
    // rows: [0..3] = scaled coords q=(sqrt3*x, sqrt3*y, sqrt2*z, w) [masked],
    //       [4..8] = f_cluster/f_center channels [masked]; scale folded into
    //       the conv weights.
    __shared__ float    s_feat[TPTS][12];  // 4800 B
    __shared__ float    s_xx[TPTS];        //  400 B  9-dim |feat|^2
    __shared__ unsigned s_idxp[TPTS][2];   //  800 B  8 neighbor idx, 8b each
    __shared__ float    s_red[4][CO];      // 1024 B
    __shared__ float    s_mean[4];         //   16 B
    __shared__ union {                     // 25600 B (time-shared)
        float stage[TPTS][4];              // raw features (A/B)
        float g[TPTS][CO];                 // g[s][o] (E/F)
    } s_u;                                 // total 32640 -> 32768 block

    const float INF = __builtin_inff();
    const int v   = blockIdx.x;
    const int tid = threadIdx.x;
    const int nv  = num_voxels[v];

    // ---- Phase A: stage raw features ----
    float4 f = make_float4(0.f, 0.f, 0.f, 0.f);
    if (tid < TPTS) {
        f = reinterpret_cast<const float4*>(features)[v * TPTS + tid];
        *reinterpret_cast<float4*>(&s_u.stage[tid][0]) = f;
    }
    __syncthreads();

    // ---- Phase B: mean of ch 0..2 over ALL 100 raw rows, / nv ----
    if (tid < 96) {
        int ch = tid >> 5, j = tid & 31;
        float p = s_u.stage[j][ch] + s_u.stage[j + 32][ch] + s_u.stage[j + 64][ch];
        if (j < 4) p += s_u.stage[j + 96][ch];
        #pragma unroll
        for (int off = 16; off >= 1; off >>= 1)
            p += __shfl_xor(p, off, 32);
        if (j == 0) s_mean[ch] = p / (float)nv;
    }
    __syncthreads();

    // ---- Phase C: build masked feat rows (scaled coords inline) + xx ----
    if (tid < TPTS) {
        float mask = (tid < nv) ? 1.0f : 0.0f;
        float c3 = (float)coors[v * 4 + 3];
        float c2 = (float)coors[v * 4 + 2];
        float r0 = f.x * mask, r1 = f.y * mask, r2 = f.z * mask, r3 = f.w * mask;
        float r4 = (f.x - s_mean[0]) * mask;
        float r5 = (f.y - s_mean[1]) * mask;
        float r6 = (f.z - s_mean[2]) * mask;
        float r7 = (f.x - (c3 * 0.2f + 0.1f)) * mask;    // VX, X_OFF
        float r8 = (f.y - (c2 * 0.2f - 39.9f)) * mask;   // VY, Y_OFF
        float xx = r0*r0 + r1*r1 + r2*r2 + r3*r3 + r4*r4
                 + r5*r5 + r6*r6 + r7*r7 + r8*r8;
        float4* rowv = reinterpret_cast<float4*>(&s_feat[tid][0]);
        rowv[0] = make_float4(1.7320508075688772f * r0,
                              1.7320508075688772f * r1,
                              1.4142135623730951f * r2, r3);
        rowv[1] = make_float4(r4, r5, r6, r7);
        rowv[2] = make_float4(r8, 0.f, 0.f, 0.f);
        s_xx[tid] = xx;
    }

    // ---- weights (all threads; scale-compensated, sign-folded) ----
    const int o  = tid & 63;               // also = lane
    const int wv = tid >> 6;               // wave id
    const float sgn = (bn_gamma[o] < 0.f) ? -1.f : 1.f;
    float w1[9], w2[9];
    #pragma unroll
    for (int c = 0; c < 9; ++c) {
        const float ws = (c == 0 || c == 1) ? 0.57735026918962576f
                       : (c == 2) ? 0.70710678118654752f : 1.f;
        float a = conv_w[o * 18 + c];
        float b = conv_w[o * 18 + 9 + c];
        w1[c] = a * sgn * ws;
        w2[c] = (b - a) * sgn * ws;
    }
    __syncthreads();

    // ---- Phase D: top-8, in-wave pair split.  Wave wv owns rows
    //      wv*32..wv*32+31; lanes 0-31 scan s in [0,h), lanes 32-63 scan
    //      [h,nv)+masked; merge across the pair via shfl_xor 32. ----
    if (wv * 32 < nv) {                    // wave-uniform dense skip
        const int trow = wv * 32 + (o & 31);
        const int bsd  = o >> 5;           // 0 = A-half, 1 = B-half
        if (trow < nv) {
            const float4 qt = *reinterpret_cast<const float4*>(&s_feat[trow][0]);
            unsigned val[KK];
            #pragma unroll
            for (int k = 0; k < KK; ++k) val[k] = 0xFFFFFFFFu;
            const int h  = (nv + 1) >> 1;
            int s        = bsd ? h  : 0;
            const int se = bsd ? nv : h;
            #pragma unroll 2
            for (; s < se; ++s) {
                const float4 qs = *reinterpret_cast<const float4*>(&s_feat[s][0]);
                ins8(val, dist_key(qt, qs, (unsigned)s));
            }
            if (bsd) {   // masked columns: e = |f_t|^2, idx nv, nv+1, ...
                int mcnt = TPTS - nv; if (mcnt > KK) mcnt = KK;
                unsigned kmb = __float_as_uint(s_xx[trow]) & 0xFFFFFF80u;
                for (int j = 0; j < mcnt; ++j)
                    ins8(val, kmb | (unsigned)(nv + j));
            }
            unsigned other[KK];            // pair partner's sorted list
            #pragma unroll
            for (int k = 0; k < KK; ++k) other[k] = __shfl_xor(val[k], 32);
            if (!bsd) {                    // A-half merges + publishes
                unsigned m[KK];
                #pragma unroll
                for (int k = 0; k < KK; ++k)   // 8 smallest of union (set-exact)
                    m[k] = umin_(val[k], other[KK - 1 - k]) & 127u;
                unsigned p0 = m[0] | (m[1] << 8) | (m[2] << 16) | (m[3] << 24);
                unsigned p1 = m[4] | (m[5] << 8) | (m[6] << 16) | (m[7] << 24);
                *reinterpret_cast<uint2*>(&s_idxp[trow][0]) = make_uint2(p0, p1);
            }
        }
    }

    // ---- zero-fill masked g rows [nv, min(nv+8,100)) — exact (+0.0) ----
    {
        int r0 = nv + wv, r1 = nv + wv + 4;
        if (r0 < TPTS) s_u.g[r0][o] = 0.f;
        if (r1 < TPTS) s_u.g[r1][o] = 0.f;
    }

    // ---- Phase E (all 4 waves, valid rows only): g[s][o] = sgn*<feat_s,W1_o> ----
    for (int sR = wv; sR < nv; sR += 4) {  // interleaved: balanced for any nv
        const float4* row = reinterpret_cast<const float4*>(&s_feat[sR][0]);
        float4 a = row[0], b = row[1];
        float c8 = s_feat[sR][8];
        float g = a.x * w1[0];
        g = __fmaf_rn(a.y, w1[1], g);
        g = __fmaf_rn(a.z, w1[2], g);
        g = __fmaf_rn(a.w, w1[3], g);
        g = __fmaf_rn(b.x, w1[4], g);
        g = __fmaf_rn(b.y, w1[5], g);
        g = __fmaf_rn(b.z, w1[6], g);
        g = __fmaf_rn(b.w, w1[7], g);
        g = __fmaf_rn(c8,  w1[8], g);
        s_u.g[sR][o] = g;                  // lane-consecutive -> conflict-free
    }
    __syncthreads();

    // ---- Phase F: acc[o] = max over valid t of (max_k g[idx]) + base[t] ----
    float acc = -INF;
    for (int tt = wv; tt < nv; tt += 4) {  // interleaved: balanced across waves
        const float4* row = reinterpret_cast<const float4*>(&s_feat[tt][0]);
        float4 a = row[0], b = row[1];
        float c8 = s_feat[tt][8];
        float base = a.x * w2[0];
        base = __fmaf_rn(a.y, w2[1], base);
        base = __fmaf_rn(a.z, w2[2], base);
        base = __fmaf_rn(a.w, w2[3], base);
        base = __fmaf_rn(b.x, w2[4], base);
        base = __fmaf_rn(b.y, w2[5], base);
        base = __fmaf_rn(b.z, w2[6], base);
        base = __fmaf_rn(b.w, w2[7], base);
        base = __fmaf_rn(c8,  w2[8], base);
        uint2 pk = *reinterpret_cast<const uint2*>(&s_idxp[tt][0]);  // broadcast
        int i0 =  pk.x        & 255, i1 = (pk.x >>  8) & 255;
        int i2 = (pk.x >> 16) & 255, i3 = (pk.x >> 24) & 255;
        int i4 =  pk.y        & 255, i5 = (pk.y >>  8) & 255;
        int i6 = (pk.y >> 16) & 255, i7 = (pk.y >> 24) & 255;
        float g0 = s_u.g[i0][o], g1 = s_u.g[i1][o], g2 = s_u.g[i2][o], g3 = s_u.g[i3][o];
        float g4 = s_u.g[i4][o], g5 = s_u.g[i5][o], g6 = s_u.g[i6][o], g7 = s_u.g[i7][o];
        float gm = fmaxf(fmaxf(fmaxf(g0, g1), fmaxf(g2, g3)),
                         fmaxf(fmaxf(g4, g5), fmaxf(g6, g7)));
        acc = fmaxf(acc, gm + base);       // base hoisted out of the k-max
    }
    s_red[wv][o] = acc;
    __syncthreads();

    // ---- Phase G: cross-wave reduce, BN + leakyReLU + mask-max, store ----
    if (tid < CO) {
        float m = fmaxf(fmaxf(s_red[0][tid], s_red[1][tid]),
                        fmaxf(s_red[2][tid], s_red[3][tid]));
        float scale = bn_gamma[tid] / sqrtf(bn_var[tid] + 0.001f);
        float bias  = bn_beta[tid] - bn_mean[tid] * scale;
        float h = m * fabsf(scale) + bias;    // m tracks sgn*h_pre
        float a = (h > 0.f) ? h : 0.2f * h;   // leaky_relu
        if (nv < TPTS) a = fmaxf(a, 0.f);     // masked rows contribute 0
        out[v * CO + tid] = a;
    }
}

extern "C" void kernel_launch(void* const* d_in, const int* in_sizes, int n_in,
                              void* d_out, int out_size, void* d_ws, size_t ws_size,
                              hipStream_t stream) {
    const float* features = (const float*)d_in[0];
    const float* conv_w   = (const float*)d_in[1];
    const float* bn_gamma = (const float*)d_in[2];
    const float* bn_beta  = (const float*)d_in[3];
    const float* bn_mean  = (const float*)d_in[4];
    const float* bn_var   = (const float*)d_in[5];
    const int*   num_vox  = (const int*)d_in[6];
    const int*   coor     = (const int*)d_in[7];
    float* outp = (float*)d_out;
    const int V = in_sizes[6];   // 4096 voxels
    dgcnn_kernel<<<V, 256, 0, stream>>>(features, conv_w, bn_gamma, bn_beta,
                                        bn_mean, bn_var, num_vox, coor, outp);
}

// Round 8
// 110.993 us; speedup vs baseline: 1.0700x; 1.0700x over previous
//
#include <hip/hip_runtime.h>

#define TPTS 100   // points per voxel (T)
#define CO   64    // output channels
#define KK   8     // k-NN

// Distances: the 9-dim edge feature is an affine image of the raw point
// (x,y,z,w), so |f_t - f_s|^2 = 3dx^2 + 3dy^2 + 2dz^2 + dw^2 for valid
// rows; masked columns (f_s = 0) give e = |f_t|^2 (9-dim norm, s_xx).
// Top-8 via packed keys: (as_uint(e) & ~0x7F) | s -- uint order == float
// order (e >= 0), ties break by lowest index.
// R8: (1) g stored as fp16 -> LDS ~19.9KB -> 8 blocks/CU static cap
//     (occupancy experiment); (2) insertion slot = v_med3_u32 (sorted-list
//     identity: min(val[k], max(val[k-1], key)) == median(val[k-1], val[k],
//     key)) -- 8 ops not 16, bit-identical; (3) balanced A/B candidate
//     split; (4) when nv<=64, non-D waves run ALL of Phase E concurrently.
__device__ __forceinline__ unsigned umin_(unsigned a, unsigned b) { return a < b ? a : b; }
__device__ __forceinline__ unsigned umax_(unsigned a, unsigned b) { return a > b ? a : b; }

__device__ __forceinline__ unsigned med3u(unsigned a, unsigned b, unsigned c) {
    unsigned d;
    asm("v_med3_u32 %0, %1, %2, %3" : "=v"(d) : "v"(a), "v"(b), "v"(c));
    return d;
}

__device__ __forceinline__ unsigned dist_key(const float4 qt, const float4 qs, unsigned s) {
    float dx = qt.x - qs.x, dy = qt.y - qs.y;
    float dz = qt.z - qs.z, dw = qt.w - qs.w;
    float e = __fmaf_rn(dx, dx, __fmaf_rn(dy, dy, __fmaf_rn(dz, dz, dw * dw)));
    return (__float_as_uint(e) & 0xFFFFFF80u) | s;
}

// insert key into sorted-ascending val[0..7] (8 smallest seen so far)
__device__ __forceinline__ void ins8(unsigned val[KK], unsigned key) {
    #pragma unroll
    for (int k = KK - 1; k >= 1; --k)      // descending: reads old val[k-1]
        val[k] = med3u(val[k - 1], val[k], key);
    val[0] = umin_(val[0], key);
}

__global__ __launch_bounds__(256) void dgcnn_kernel(
    const float* __restrict__ features,   // [V][100][4]
    const float* __restrict__ conv_w,     // [64][18]
    const float* __restrict__ bn_gamma,
    const float* __restrict__ bn_beta,
    const float* __restrict__ bn_mean,
    const float* __restrict__ bn_var,
    const int*  __restrict__ num_voxels,  // [V]
    const int*  __restrict__ coors,       // [V][4]
    float* __restrict__ out)              // [V][64]
{
    // rows: [0..3] = scaled coords q=(sqrt3*x, sqrt3*y, sqrt2*z, w) [masked],
    //       [4..8] = f_cluster/f_center channels [masked]; scale folded into
    //       the conv weights.
    __shared__ float    s_feat[TPTS][12];  // 4800 B
    __shared__ float    s_xx[TPTS];        //  400 B  9-dim |feat|^2
    __shared__ unsigned s_idxp[TPTS][2];   //  800 B  8 neighbor idx, 8b each
    __shared__ float    s_red[4][CO];      // 1024 B
    __shared__ float    s_mean[4];         //   16 B
    __shared__ union {                     // 12800 B (time-shared)
        float    stage[TPTS][4];           // raw features (A/B)
        _Float16 g16[TPTS][CO];            // g[s][o] fp16 (E/F)
    } s_u;                                 // total ~19.9 KB -> 8 blocks/CU

    const float INF = __builtin_inff();
    const int v   = blockIdx.x;
    const int tid = threadIdx.x;
    const int nv  = num_voxels[v];

    // ---- Phase A: stage raw features ----
    float4 f = make_float4(0.f, 0.f, 0.f, 0.f);
    if (tid < TPTS) {
        f = reinterpret_cast<const float4*>(features)[v * TPTS + tid];
        *reinterpret_cast<float4*>(&s_u.stage[tid][0]) = f;
    }
    __syncthreads();

    // ---- Phase B: mean of ch 0..2 over ALL 100 raw rows, / nv ----
    if (tid < 96) {
        int ch = tid >> 5, j = tid & 31;
        float p = s_u.stage[j][ch] + s_u.stage[j + 32][ch] + s_u.stage[j + 64][ch];
        if (j < 4) p += s_u.stage[j + 96][ch];
        #pragma unroll
        for (int off = 16; off >= 1; off >>= 1)
            p += __shfl_xor(p, off, 32);
        if (j == 0) s_mean[ch] = p / (float)nv;
    }
    __syncthreads();

    // ---- Phase C: build masked feat rows (scaled coords inline) + xx ----
    if (tid < TPTS) {
        float mask = (tid < nv) ? 1.0f : 0.0f;
        float c3 = (float)coors[v * 4 + 3];
        float c2 = (float)coors[v * 4 + 2];
        float r0 = f.x * mask, r1 = f.y * mask, r2 = f.z * mask, r3 = f.w * mask;
        float r4 = (f.x - s_mean[0]) * mask;
        float r5 = (f.y - s_mean[1]) * mask;
        float r6 = (f.z - s_mean[2]) * mask;
        float r7 = (f.x - (c3 * 0.2f + 0.1f)) * mask;    // VX, X_OFF
        float r8 = (f.y - (c2 * 0.2f - 39.9f)) * mask;   // VY, Y_OFF
        float xx = r0*r0 + r1*r1 + r2*r2 + r3*r3 + r4*r4
                 + r5*r5 + r6*r6 + r7*r7 + r8*r8;
        float4* rowv = reinterpret_cast<float4*>(&s_feat[tid][0]);
        rowv[0] = make_float4(1.7320508075688772f * r0,
                              1.7320508075688772f * r1,
                              1.4142135623730951f * r2, r3);
        rowv[1] = make_float4(r4, r5, r6, r7);
        rowv[2] = make_float4(r8, 0.f, 0.f, 0.f);
        s_xx[tid] = xx;
    }

    // ---- weights (all threads; scale-compensated, sign-folded) ----
    const int o  = tid & 63;               // also = lane
    const int wv = tid >> 6;               // wave id
    const float sgn = (bn_gamma[o] < 0.f) ? -1.f : 1.f;
    float w1[9], w2[9];
    #pragma unroll
    for (int c = 0; c < 9; ++c) {
        const float ws = (c == 0 || c == 1) ? 0.57735026918962576f
                       : (c == 2) ? 0.70710678118654752f : 1.f;
        float a = conv_w[o * 18 + c];
        float b = conv_w[o * 18 + 9 + c];
        w1[c] = a * sgn * ws;
        w2[c] = (b - a) * sgn * ws;
    }
    __syncthreads();

    const int nd = (nv + 31) >> 5;         // # D-waves (1..4)

    // ---- Phase D (waves 0..nd-1): top-8, in-wave pair split. Wave wv owns
    //      rows wv*32..+31; lanes 0-31 scan [0,ha), lanes 32-63 scan
    //      [ha,nv)+masked (ha balanced); merge via shfl_xor 32. ----
    if (wv < nd) {
        const int trow = wv * 32 + (o & 31);
        const int bsd  = o >> 5;           // 0 = A-half, 1 = B-half
        if (trow < nv) {
            const float4 qt = *reinterpret_cast<const float4*>(&s_feat[trow][0]);
            unsigned val[KK];
            #pragma unroll
            for (int k = 0; k < KK; ++k) val[k] = 0xFFFFFFFFu;
            int mcnt = TPTS - nv; if (mcnt > KK) mcnt = KK;
            int ha = (nv + mcnt + 1) >> 1; if (ha > nv) ha = nv;  // balance
            int s        = bsd ? ha : 0;
            const int se = bsd ? nv : ha;
            #pragma unroll 2
            for (; s < se; ++s) {
                const float4 qs = *reinterpret_cast<const float4*>(&s_feat[s][0]);
                ins8(val, dist_key(qt, qs, (unsigned)s));
            }
            if (bsd) {   // masked columns: e = |f_t|^2, idx nv, nv+1, ...
                unsigned kmb = __float_as_uint(s_xx[trow]) & 0xFFFFFF80u;
                for (int j = 0; j < mcnt; ++j)
                    ins8(val, kmb | (unsigned)(nv + j));
            }
            unsigned other[KK];            // pair partner's sorted list
            #pragma unroll
            for (int k = 0; k < KK; ++k) other[k] = __shfl_xor(val[k], 32);
            if (!bsd) {                    // A-half merges + publishes
                unsigned m[KK];
                #pragma unroll
                for (int k = 0; k < KK; ++k)   // 8 smallest of union (set-exact)
                    m[k] = umin_(val[k], other[KK - 1 - k]) & 127u;
                unsigned p0 = m[0] | (m[1] << 8) | (m[2] << 16) | (m[3] << 24);
                unsigned p1 = m[4] | (m[5] << 8) | (m[6] << 16) | (m[7] << 24);
                *reinterpret_cast<uint2*>(&s_idxp[trow][0]) = make_uint2(p0, p1);
            }
        }
    }

    // ---- zero-fill masked g rows [nv, min(nv+8,100)) — exact (+0.0) ----
    {
        int r0 = nv + wv, r1 = nv + wv + 4;
        if (r0 < TPTS) s_u.g16[r0][o] = (_Float16)0.f;
        if (r1 < TPTS) s_u.g16[r1][o] = (_Float16)0.f;
    }

    // ---- Phase E: g[s][o] = sgn*<feat_s,W1_o>, fp16 store.  When nv<=64
    //      (nd<=2) the free waves do ALL of E concurrently with D. ----
    {
        int sR, step;
        if (nd <= 2) { sR = (wv >= nd) ? (wv - nd) : nv; step = 4 - nd; }
        else         { sR = wv;                          step = 4;      }
        for (; sR < nv; sR += step) {
            const float4* row = reinterpret_cast<const float4*>(&s_feat[sR][0]);
            float4 a = row[0], b = row[1];
            float c8 = s_feat[sR][8];
            float g = a.x * w1[0];
            g = __fmaf_rn(a.y, w1[1], g);
            g = __fmaf_rn(a.z, w1[2], g);
            g = __fmaf_rn(a.w, w1[3], g);
            g = __fmaf_rn(b.x, w1[4], g);
            g = __fmaf_rn(b.y, w1[5], g);
            g = __fmaf_rn(b.z, w1[6], g);
            g = __fmaf_rn(b.w, w1[7], g);
            g = __fmaf_rn(c8,  w1[8], g);
            s_u.g16[sR][o] = (_Float16)g;  // lane-consecutive 2B
        }
    }
    __syncthreads();

    // ---- Phase F: acc[o] = max over valid t of (max_k g[idx]) + base[t] ----
    float acc = -INF;
    for (int tt = wv; tt < nv; tt += 4) {  // interleaved: balanced across waves
        const float4* row = reinterpret_cast<const float4*>(&s_feat[tt][0]);
        float4 a = row[0], b = row[1];
        float c8 = s_feat[tt][8];
        float base = a.x * w2[0];
        base = __fmaf_rn(a.y, w2[1], base);
        base = __fmaf_rn(a.z, w2[2], base);
        base = __fmaf_rn(a.w, w2[3], base);
        base = __fmaf_rn(b.x, w2[4], base);
        base = __fmaf_rn(b.y, w2[5], base);
        base = __fmaf_rn(b.z, w2[6], base);
        base = __fmaf_rn(b.w, w2[7], base);
        base = __fmaf_rn(c8,  w2[8], base);
        uint2 pk = *reinterpret_cast<const uint2*>(&s_idxp[tt][0]);  // broadcast
        int i0 =  pk.x        & 255, i1 = (pk.x >>  8) & 255;
        int i2 = (pk.x >> 16) & 255, i3 = (pk.x >> 24) & 255;
        int i4 =  pk.y        & 255, i5 = (pk.y >>  8) & 255;
        int i6 = (pk.y >> 16) & 255, i7 = (pk.y >> 24) & 255;
        float g0 = (float)s_u.g16[i0][o], g1 = (float)s_u.g16[i1][o];
        float g2 = (float)s_u.g16[i2][o], g3 = (float)s_u.g16[i3][o];
        float g4 = (float)s_u.g16[i4][o], g5 = (float)s_u.g16[i5][o];
        float g6 = (float)s_u.g16[i6][o], g7 = (float)s_u.g16[i7][o];
        float gm = fmaxf(fmaxf(fmaxf(g0, g1), fmaxf(g2, g3)),
                         fmaxf(fmaxf(g4, g5), fmaxf(g6, g7)));
        acc = fmaxf(acc, gm + base);       // base hoisted out of the k-max
    }
    s_red[wv][o] = acc;
    __syncthreads();

    // ---- Phase G: cross-wave reduce, BN + leakyReLU + mask-max, store ----
    if (tid < CO) {
        float m = fmaxf(fmaxf(s_red[0][tid], s_red[1][tid]),
                        fmaxf(s_red[2][tid], s_red[3][tid]));
        float scale = bn_gamma[tid] / sqrtf(bn_var[tid] + 0.001f);
        float bias  = bn_beta[tid] - bn_mean[tid] * scale;
        float h = m * fabsf(scale) + bias;    // m tracks sgn*h_pre
        float a = (h > 0.f) ? h : 0.2f * h;   // leaky_relu
        if (nv < TPTS) a = fmaxf(a, 0.f);     // masked rows contribute 0
        out[v * CO + tid] = a;
    }
}

extern "C" void kernel_launch(void* const* d_in, const int* in_sizes, int n_in,
                              void* d_out, int out_size, void* d_ws, size_t ws_size,
                              hipStream_t stream) {
    const float* features = (const float*)d_in[0];
    const float* conv_w   = (const float*)d_in[1];
    const float* bn_gamma = (const float*)d_in[2];
    const float* bn_beta  = (const float*)d_in[3];
    const float* bn_mean  = (const float*)d_in[4];
    const float* bn_var   = (const float*)d_in[5];
    const int*   num_vox  = (const int*)d_in[6];
    const int*   coor     = (const int*)d_in[7];
    float* outp = (float*)d_out;
    const int V = in_sizes[6];   // 4096 voxels
    dgcnn_kernel<<<V, 256, 0, stream>>>(features, conv_w, bn_gamma, bn_beta,
                                        bn_mean, bn_var, num_vox, coor, outp);
}

// Round 9
// 108.263 us; speedup vs baseline: 1.0970x; 1.0252x over previous
//
#include <hip/hip_runtime.h>

#define TPTS 100   // points per voxel (T)
#define CO   64    // output channels
#define KK   8     // k-NN
#define NW   8     // waves per block (512 threads)

// Distances: the 9-dim edge feature is an affine image of the raw point
// (x,y,z,w), so |f_t - f_s|^2 = 3dx^2 + 3dy^2 + 2dz^2 + dw^2 for valid
// rows; masked columns (f_s = 0) give e = |f_t|^2 (9-dim norm, s_xx).
// Top-8 via packed keys: (as_uint(e) & ~0x7F) | s -- uint order == float
// order (e >= 0), ties break by lowest index.
// R9: 512-thread blocks (8 waves) at the SAME ~20KB LDS. R7/R8 counters fit
// an effective ~64KB/CU LDS scheduling pool (32768B->2.25 blk, 19968B->3.3
// blk); more waves per LDS allocation is the only residency lever left.
// Also: F's 8-way neighbor max done in fp16 (1 cvt instead of 8).
__device__ __forceinline__ unsigned umin_(unsigned a, unsigned b) { return a < b ? a : b; }
__device__ __forceinline__ unsigned umax_(unsigned a, unsigned b) { return a > b ? a : b; }
__device__ __forceinline__ _Float16 hmax_(_Float16 a, _Float16 b) { return a > b ? a : b; }

__device__ __forceinline__ unsigned med3u(unsigned a, unsigned b, unsigned c) {
    unsigned d;
    asm("v_med3_u32 %0, %1, %2, %3" : "=v"(d) : "v"(a), "v"(b), "v"(c));
    return d;
}

__device__ __forceinline__ unsigned dist_key(const float4 qt, const float4 qs, unsigned s) {
    float dx = qt.x - qs.x, dy = qt.y - qs.y;
    float dz = qt.z - qs.z, dw = qt.w - qs.w;
    float e = __fmaf_rn(dx, dx, __fmaf_rn(dy, dy, __fmaf_rn(dz, dz, dw * dw)));
    return (__float_as_uint(e) & 0xFFFFFF80u) | s;
}

// insert key into sorted-ascending val[0..7]; med3 identity (bit-identical
// to serial insertion): slots independent, depth 2.
__device__ __forceinline__ void ins8(unsigned val[KK], unsigned key) {
    #pragma unroll
    for (int k = KK - 1; k >= 1; --k)
        val[k] = med3u(val[k - 1], val[k], key);
    val[0] = umin_(val[0], key);
}

__global__ __launch_bounds__(512) void dgcnn_kernel(
    const float* __restrict__ features,   // [V][100][4]
    const float* __restrict__ conv_w,     // [64][18]
    const float* __restrict__ bn_gamma,
    const float* __restrict__ bn_beta,
    const float* __restrict__ bn_mean,
    const float* __restrict__ bn_var,
    const int*  __restrict__ num_voxels,  // [V]
    const int*  __restrict__ coors,       // [V][4]
    float* __restrict__ out)              // [V][64]
{
    __shared__ float    s_feat[TPTS][12];  // 4800 B
    __shared__ float    s_xx[TPTS];        //  400 B  9-dim |feat|^2
    __shared__ unsigned s_idxp[TPTS][2];   //  800 B  8 neighbor idx, 8b each
    __shared__ float    s_red[NW][CO];     // 2048 B
    __shared__ float    s_mean[4];         //   16 B
    __shared__ union {                     // 12800 B (time-shared)
        float    stage[TPTS][4];           // raw features (A/B)
        _Float16 g16[TPTS][CO];            // g[s][o] fp16 (E/F)
    } s_u;                                 // total 20864 B

    const float INF = __builtin_inff();
    const int v   = blockIdx.x;
    const int tid = threadIdx.x;
    const int nv  = num_voxels[v];

    // ---- Phase A: stage raw features ----
    float4 f = make_float4(0.f, 0.f, 0.f, 0.f);
    if (tid < TPTS) {
        f = reinterpret_cast<const float4*>(features)[v * TPTS + tid];
        *reinterpret_cast<float4*>(&s_u.stage[tid][0]) = f;
    }
    __syncthreads();

    // ---- Phase B: mean of ch 0..2 over ALL 100 raw rows, / nv ----
    if (tid < 96) {
        int ch = tid >> 5, j = tid & 31;
        float p = s_u.stage[j][ch] + s_u.stage[j + 32][ch] + s_u.stage[j + 64][ch];
        if (j < 4) p += s_u.stage[j + 96][ch];
        #pragma unroll
        for (int off = 16; off >= 1; off >>= 1)
            p += __shfl_xor(p, off, 32);
        if (j == 0) s_mean[ch] = p / (float)nv;
    }
    __syncthreads();

    // ---- Phase C: build masked feat rows (scaled coords inline) + xx ----
    if (tid < TPTS) {
        float mask = (tid < nv) ? 1.0f : 0.0f;
        float c3 = (float)coors[v * 4 + 3];
        float c2 = (float)coors[v * 4 + 2];
        float r0 = f.x * mask, r1 = f.y * mask, r2 = f.z * mask, r3 = f.w * mask;
        float r4 = (f.x - s_mean[0]) * mask;
        float r5 = (f.y - s_mean[1]) * mask;
        float r6 = (f.z - s_mean[2]) * mask;
        float r7 = (f.x - (c3 * 0.2f + 0.1f)) * mask;    // VX, X_OFF
        float r8 = (f.y - (c2 * 0.2f - 39.9f)) * mask;   // VY, Y_OFF
        float xx = r0*r0 + r1*r1 + r2*r2 + r3*r3 + r4*r4
                 + r5*r5 + r6*r6 + r7*r7 + r8*r8;
        float4* rowv = reinterpret_cast<float4*>(&s_feat[tid][0]);
        rowv[0] = make_float4(1.7320508075688772f * r0,
                              1.7320508075688772f * r1,
                              1.4142135623730951f * r2, r3);
        rowv[1] = make_float4(r4, r5, r6, r7);
        rowv[2] = make_float4(r8, 0.f, 0.f, 0.f);
        s_xx[tid] = xx;
    }

    // ---- weights (all threads; scale-compensated, sign-folded) ----
    const int o  = tid & 63;               // lane
    const int wv = tid >> 6;               // wave id 0..7
    const float sgn = (bn_gamma[o] < 0.f) ? -1.f : 1.f;
    float w1[9], w2[9];
    #pragma unroll
    for (int c = 0; c < 9; ++c) {
        const float ws = (c == 0 || c == 1) ? 0.57735026918962576f
                       : (c == 2) ? 0.70710678118654752f : 1.f;
        float a = conv_w[o * 18 + c];
        float b = conv_w[o * 18 + 9 + c];
        w1[c] = a * sgn * ws;
        w2[c] = (b - a) * sgn * ws;
    }
    __syncthreads();

    const int nd = (nv + 31) >> 5;         // # D-waves (1..4); >=4 waves free

    // ---- zero-fill masked g rows [nv, min(nv+8,100)) — exact (+0.0) ----
    {
        int r0 = nv + wv;                  // 8 waves cover all 8 masked rows
        if (r0 < TPTS) s_u.g16[r0][o] = (_Float16)0.f;
    }

    if (wv < nd) {
        // ---- Phase D: top-8, in-wave pair split. Wave wv owns rows
        //      wv*32..+31; lanes 0-31 scan [0,ha), lanes 32-63 scan
        //      [ha,nv)+masked (balanced); merge via shfl_xor 32. ----
        const int trow = wv * 32 + (o & 31);
        const int bsd  = o >> 5;           // 0 = A-half, 1 = B-half
        if (trow < nv) {
            const float4 qt = *reinterpret_cast<const float4*>(&s_feat[trow][0]);
            unsigned val[KK];
            #pragma unroll
            for (int k = 0; k < KK; ++k) val[k] = 0xFFFFFFFFu;
            int mcnt = TPTS - nv; if (mcnt > KK) mcnt = KK;
            int ha = (nv + mcnt + 1) >> 1; if (ha > nv) ha = nv;  // balance
            int s        = bsd ? ha : 0;
            const int se = bsd ? nv : ha;
            #pragma unroll 2
            for (; s < se; ++s) {
                const float4 qs = *reinterpret_cast<const float4*>(&s_feat[s][0]);
                ins8(val, dist_key(qt, qs, (unsigned)s));
            }
            if (bsd) {   // masked columns: e = |f_t|^2, idx nv, nv+1, ...
                unsigned kmb = __float_as_uint(s_xx[trow]) & 0xFFFFFF80u;
                for (int j = 0; j < mcnt; ++j)
                    ins8(val, kmb | (unsigned)(nv + j));
            }
            unsigned other[KK];            // pair partner's sorted list
            #pragma unroll
            for (int k = 0; k < KK; ++k) other[k] = __shfl_xor(val[k], 32);
            if (!bsd) {                    // A-half merges + publishes
                unsigned m[KK];
                #pragma unroll
                for (int k = 0; k < KK; ++k)   // 8 smallest of union (set-exact)
                    m[k] = umin_(val[k], other[KK - 1 - k]) & 127u;
                unsigned p0 = m[0] | (m[1] << 8) | (m[2] << 16) | (m[3] << 24);
                unsigned p1 = m[4] | (m[5] << 8) | (m[6] << 16) | (m[7] << 24);
                *reinterpret_cast<uint2*>(&s_idxp[trow][0]) = make_uint2(p0, p1);
            }
        }
    } else {
        // ---- Phase E (waves nd..7, ALWAYS >=4): g[s][o] = sgn*<feat_s,W1_o> ----
        const int step = NW - nd;
        for (int sR = wv - nd; sR < nv; sR += step) {
            const float4* row = reinterpret_cast<const float4*>(&s_feat[sR][0]);
            float4 a = row[0], b = row[1];
            float c8 = s_feat[sR][8];
            float g = a.x * w1[0];
            g = __fmaf_rn(a.y, w1[1], g);
            g = __fmaf_rn(a.z, w1[2], g);
            g = __fmaf_rn(a.w, w1[3], g);
            g = __fmaf_rn(b.x, w1[4], g);
            g = __fmaf_rn(b.y, w1[5], g);
            g = __fmaf_rn(b.z, w1[6], g);
            g = __fmaf_rn(b.w, w1[7], g);
            g = __fmaf_rn(c8,  w1[8], g);
            s_u.g16[sR][o] = (_Float16)g;  // lane-consecutive 2B
        }
    }
    __syncthreads();

    // ---- Phase F: acc[o] = max over valid t of (max_k g[idx]) + base[t] ----
    float acc = -INF;
    for (int tt = wv; tt < nv; tt += NW) { // interleaved across 8 waves
        const float4* row = reinterpret_cast<const float4*>(&s_feat[tt][0]);
        float4 a = row[0], b = row[1];
        float c8 = s_feat[tt][8];
        float base = a.x * w2[0];
        base = __fmaf_rn(a.y, w2[1], base);
        base = __fmaf_rn(a.z, w2[2], base);
        base = __fmaf_rn(a.w, w2[3], base);
        base = __fmaf_rn(b.x, w2[4], base);
        base = __fmaf_rn(b.y, w2[5], base);
        base = __fmaf_rn(b.z, w2[6], base);
        base = __fmaf_rn(b.w, w2[7], base);
        base = __fmaf_rn(c8,  w2[8], base);
        uint2 pk = *reinterpret_cast<const uint2*>(&s_idxp[tt][0]);  // broadcast
        int i0 =  pk.x        & 255, i1 = (pk.x >>  8) & 255;
        int i2 = (pk.x >> 16) & 255, i3 = (pk.x >> 24) & 255;
        int i4 =  pk.y        & 255, i5 = (pk.y >>  8) & 255;
        int i6 = (pk.y >> 16) & 255, i7 = (pk.y >> 24) & 255;
        // 8-way max in fp16 (exact: max commutes with exact f16->f32 cvt)
        _Float16 g0 = s_u.g16[i0][o], g1 = s_u.g16[i1][o];
        _Float16 g2 = s_u.g16[i2][o], g3 = s_u.g16[i3][o];
        _Float16 g4 = s_u.g16[i4][o], g5 = s_u.g16[i5][o];
        _Float16 g6 = s_u.g16[i6][o], g7 = s_u.g16[i7][o];
        _Float16 gm = hmax_(hmax_(hmax_(g0, g1), hmax_(g2, g3)),
                            hmax_(hmax_(g4, g5), hmax_(g6, g7)));
        acc = fmaxf(acc, (float)gm + base);   // base hoisted out of the k-max
    }
    s_red[wv][o] = acc;
    __syncthreads();

    // ---- Phase G: cross-wave reduce, BN + leakyReLU + mask-max, store ----
    if (tid < CO) {
        float m = s_red[0][tid];
        #pragma unroll
        for (int i = 1; i < NW; ++i) m = fmaxf(m, s_red[i][tid]);
        float scale = bn_gamma[tid] / sqrtf(bn_var[tid] + 0.001f);
        float bias  = bn_beta[tid] - bn_mean[tid] * scale;
        float h = m * fabsf(scale) + bias;    // m tracks sgn*h_pre
        float a = (h > 0.f) ? h : 0.2f * h;   // leaky_relu
        if (nv < TPTS) a = fmaxf(a, 0.f);     // masked rows contribute 0
        out[v * CO + tid] = a;
    }
}

extern "C" void kernel_launch(void* const* d_in, const int* in_sizes, int n_in,
                              void* d_out, int out_size, void* d_ws, size_t ws_size,
                              hipStream_t stream) {
    const float* features = (const float*)d_in[0];
    const float* conv_w   = (const float*)d_in[1];
    const float* bn_gamma = (const float*)d_in[2];
    const float* bn_beta  = (const float*)d_in[3];
    const float* bn_mean  = (const float*)d_in[4];
    const float* bn_var   = (const float*)d_in[5];
    const int*   num_vox  = (const int*)d_in[6];
    const int*   coor     = (const int*)d_in[7];
    float* outp = (float*)d_out;
    const int V = in_sizes[6];   // 4096 voxels
    dgcnn_kernel<<<V, 512, 0, stream>>>(features, conv_w, bn_gamma, bn_beta,
                                        bn_mean, bn_var, num_vox, coor, outp);
}

// Round 10
// 108.032 us; speedup vs baseline: 1.0993x; 1.0021x over previous
//
#include <hip/hip_runtime.h>

#define TPTS 100   // points per voxel (T)
#define CO   64    // output channels
#define KK   8     // k-NN
#define NW   8     // waves per block (512 threads)

// Distances: the 9-dim edge feature is an affine image of the raw point
// p=(x,y,z,w): |f_t - f_s|^2 = 3dx^2+3dy^2+2dz^2+dw^2 (valid rows); masked
// columns give e = |f_t|^2 (9-dim norm).  The SAME affine structure means
// <feat_t, W> = <p_t, Weff> + const_v  (valid rows), so the 9-ch feature
// matrix never materializes: LDS holds only scaled coords q[100][4].
// Top-8 via packed keys: (as_uint(e) & ~0x7F) | s -- uint order == float
// order (e >= 0), ties break by lowest index.
// R10: affine-collapsed E/F (4 FMA each), LDS 15616 B -> 4 blocks/CU under
// the empirical ~64KB scheduling pool; s_red folded into the g16 region.
__device__ __forceinline__ unsigned umin_(unsigned a, unsigned b) { return a < b ? a : b; }
__device__ __forceinline__ _Float16 hmax_(_Float16 a, _Float16 b) { return a > b ? a : b; }

__device__ __forceinline__ unsigned med3u(unsigned a, unsigned b, unsigned c) {
    unsigned d;
    asm("v_med3_u32 %0, %1, %2, %3" : "=v"(d) : "v"(a), "v"(b), "v"(c));
    return d;
}

__device__ __forceinline__ unsigned dist_key(const float4 qt, const float4 qs, unsigned s) {
    float dx = qt.x - qs.x, dy = qt.y - qs.y;
    float dz = qt.z - qs.z, dw = qt.w - qs.w;
    float e = __fmaf_rn(dx, dx, __fmaf_rn(dy, dy, __fmaf_rn(dz, dz, dw * dw)));
    return (__float_as_uint(e) & 0xFFFFFF80u) | s;
}

// insert key into sorted-ascending val[0..7]; med3 identity (bit-identical
// to serial insertion): slots independent, depth 2.
__device__ __forceinline__ void ins8(unsigned val[KK], unsigned key) {
    #pragma unroll
    for (int k = KK - 1; k >= 1; --k)
        val[k] = med3u(val[k - 1], val[k], key);
    val[0] = umin_(val[0], key);
}

__global__ __launch_bounds__(512) void dgcnn_kernel(
    const float* __restrict__ features,   // [V][100][4]
    const float* __restrict__ conv_w,     // [64][18]
    const float* __restrict__ bn_gamma,
    const float* __restrict__ bn_beta,
    const float* __restrict__ bn_mean,
    const float* __restrict__ bn_var,
    const int*  __restrict__ num_voxels,  // [V]
    const int*  __restrict__ coors,       // [V][4]
    float* __restrict__ out)              // [V][64]
{
    __shared__ float    s_q[TPTS][4];      // 1600 B scaled coords (fp32, exact D)
    __shared__ float    s_xx[TPTS];        //  400 B 9-dim |feat|^2
    __shared__ unsigned s_idxp[TPTS][2];   //  800 B 8 neighbor idx, 8b each
    __shared__ float    s_mean[4];         //   16 B
    __shared__ union {                     // 12800 B (time-shared)
        float    stage[TPTS][4];           // raw features (A/B)
        _Float16 g16[TPTS][CO];            // g[s][o] fp16 (E/F)
        float    red[NW][CO];              // wave partials (post-F, barriered)
    } s_u;                                 // total 15616 B -> 4 blocks/CU

    const float INF = __builtin_inff();
    const int v   = blockIdx.x;
    const int tid = threadIdx.x;
    const int nv  = num_voxels[v];

    // ---- Phase A: stage raw features ----
    float4 f = make_float4(0.f, 0.f, 0.f, 0.f);
    if (tid < TPTS) {
        f = reinterpret_cast<const float4*>(features)[v * TPTS + tid];
        *reinterpret_cast<float4*>(&s_u.stage[tid][0]) = f;
    }
    __syncthreads();

    // ---- Phase B: mean of ch 0..2 over ALL 100 raw rows, / nv ----
    if (tid < 96) {
        int ch = tid >> 5, j = tid & 31;
        float p = s_u.stage[j][ch] + s_u.stage[j + 32][ch] + s_u.stage[j + 64][ch];
        if (j < 4) p += s_u.stage[j + 96][ch];
        #pragma unroll
        for (int off = 16; off >= 1; off >>= 1)
            p += __shfl_xor(p, off, 32);
        if (j == 0) s_mean[ch] = p / (float)nv;
    }
    __syncthreads();

    // per-voxel center (uniform scalar loads)
    const float cx = (float)coors[v * 4 + 3] * 0.2f + 0.1f;    // VX, X_OFF
    const float cy = (float)coors[v * 4 + 2] * 0.2f - 39.9f;   // VY, Y_OFF
    const float m0 = s_mean[0], m1 = s_mean[1], m2 = s_mean[2];

    // ---- Phase C: masked scaled coords q + 9-dim norm xx ----
    if (tid < TPTS) {
        float mask = (tid < nv) ? 1.0f : 0.0f;
        float r0 = f.x * mask, r1 = f.y * mask, r2 = f.z * mask, r3 = f.w * mask;
        float r4 = (f.x - m0) * mask;
        float r5 = (f.y - m1) * mask;
        float r6 = (f.z - m2) * mask;
        float r7 = (f.x - cx) * mask;
        float r8 = (f.y - cy) * mask;
        float xx = r0*r0 + r1*r1 + r2*r2 + r3*r3 + r4*r4
                 + r5*r5 + r6*r6 + r7*r7 + r8*r8;
        *reinterpret_cast<float4*>(&s_q[tid][0]) =
            make_float4(1.7320508075688772f * r0,
                        1.7320508075688772f * r1,
                        1.4142135623730951f * r2, r3);
        s_xx[tid] = xx;
    }

    // ---- effective weights (affine collapse; applied to scaled q) ----
    // <feat, W> = <p, Weff> + const_v on valid rows; q = S*p with
    // S = diag(sqrt3, sqrt3, sqrt2, 1) -> use Weff/S against q.
    const int o  = tid & 63;               // lane
    const int wv = tid >> 6;               // wave id 0..7
    const float sgn = (bn_gamma[o] < 0.f) ? -1.f : 1.f;
    float w1r[9], w2r[9];
    #pragma unroll
    for (int c = 0; c < 9; ++c) {
        float a = conv_w[o * 18 + c];
        float b = conv_w[o * 18 + 9 + c];
        w1r[c] = a * sgn;
        w2r[c] = (b - a) * sgn;
    }
    const float i3 = 0.57735026918962576f, i2 = 0.70710678118654752f;
    float wq1[4], wq2[4];
    wq1[0] = (w1r[0] + w1r[4] + w1r[7]) * i3;
    wq1[1] = (w1r[1] + w1r[5] + w1r[8]) * i3;
    wq1[2] = (w1r[2] + w1r[6]) * i2;
    wq1[3] = w1r[3];
    wq2[0] = (w2r[0] + w2r[4] + w2r[7]) * i3;
    wq2[1] = (w2r[1] + w2r[5] + w2r[8]) * i3;
    wq2[2] = (w2r[2] + w2r[6]) * i2;
    wq2[3] = w2r[3];
    const float c1v = -(w1r[4]*m0 + w1r[5]*m1 + w1r[6]*m2 + w1r[7]*cx + w1r[8]*cy);
    const float c2v = -(w2r[4]*m0 + w2r[5]*m1 + w2r[6]*m2 + w2r[7]*cx + w2r[8]*cy);
    __syncthreads();

    const int nd = (nv + 31) >> 5;         // # D-waves (1..4); >=4 waves free

    // ---- zero-fill masked g rows [nv, min(nv+8,100)) — exact (+0.0) ----
    {
        int r0 = nv + wv;                  // 8 waves cover all 8 masked rows
        if (r0 < TPTS) s_u.g16[r0][o] = (_Float16)0.f;
    }

    if (wv < nd) {
        // ---- Phase D: top-8, in-wave pair split. Wave wv owns rows
        //      wv*32..+31; lanes 0-31 scan [0,ha), lanes 32-63 scan
        //      [ha,nv)+masked (balanced); merge via shfl_xor 32. ----
        const int trow = wv * 32 + (o & 31);
        const int bsd  = o >> 5;           // 0 = A-half, 1 = B-half
        if (trow < nv) {
            const float4 qt = *reinterpret_cast<const float4*>(&s_q[trow][0]);
            unsigned val[KK];
            #pragma unroll
            for (int k = 0; k < KK; ++k) val[k] = 0xFFFFFFFFu;
            int mcnt = TPTS - nv; if (mcnt > KK) mcnt = KK;
            int ha = (nv + mcnt + 1) >> 1; if (ha > nv) ha = nv;  // balance
            int s        = bsd ? ha : 0;
            const int se = bsd ? nv : ha;
            #pragma unroll 2
            for (; s < se; ++s) {
                const float4 qs = *reinterpret_cast<const float4*>(&s_q[s][0]);
                ins8(val, dist_key(qt, qs, (unsigned)s));
            }
            if (bsd) {   // masked columns: e = |f_t|^2, idx nv, nv+1, ...
                unsigned kmb = __float_as_uint(s_xx[trow]) & 0xFFFFFF80u;
                for (int j = 0; j < mcnt; ++j)
                    ins8(val, kmb | (unsigned)(nv + j));
            }
            unsigned other[KK];            // pair partner's sorted list
            #pragma unroll
            for (int k = 0; k < KK; ++k) other[k] = __shfl_xor(val[k], 32);
            if (!bsd) {                    // A-half merges + publishes
                unsigned m[KK];
                #pragma unroll
                for (int k = 0; k < KK; ++k)   // 8 smallest of union (set-exact)
                    m[k] = umin_(val[k], other[KK - 1 - k]) & 127u;
                unsigned p0 = m[0] | (m[1] << 8) | (m[2] << 16) | (m[3] << 24);
                unsigned p1 = m[4] | (m[5] << 8) | (m[6] << 16) | (m[7] << 24);
                *reinterpret_cast<uint2*>(&s_idxp[trow][0]) = make_uint2(p0, p1);
            }
        }
    } else {
        // ---- Phase E (waves nd..7, always >=4): g = <q,wq1> + c1v ----
        const int step = NW - nd;
        for (int sR = wv - nd; sR < nv; sR += step) {
            const float4 q = *reinterpret_cast<const float4*>(&s_q[sR][0]);
            float g = c1v;
            g = __fmaf_rn(q.x, wq1[0], g);
            g = __fmaf_rn(q.y, wq1[1], g);
            g = __fmaf_rn(q.z, wq1[2], g);
            g = __fmaf_rn(q.w, wq1[3], g);
            s_u.g16[sR][o] = (_Float16)g;  // lane-consecutive 2B
        }
    }
    __syncthreads();

    // ---- Phase F: acc[o] = max over valid t of (max_k g[idx]) + base[t] ----
    float acc = -INF;
    for (int tt = wv; tt < nv; tt += NW) { // interleaved across 8 waves
        const float4 q = *reinterpret_cast<const float4*>(&s_q[tt][0]);
        float base = c2v;
        base = __fmaf_rn(q.x, wq2[0], base);
        base = __fmaf_rn(q.y, wq2[1], base);
        base = __fmaf_rn(q.z, wq2[2], base);
        base = __fmaf_rn(q.w, wq2[3], base);
        uint2 pk = *reinterpret_cast<const uint2*>(&s_idxp[tt][0]);  // broadcast
        int i0 =  pk.x        & 255, i1 = (pk.x >>  8) & 255;
        int i2 = (pk.x >> 16) & 255, i3_ = (pk.x >> 24) & 255;
        int i4 =  pk.y        & 255, i5 = (pk.y >>  8) & 255;
        int i6 = (pk.y >> 16) & 255, i7 = (pk.y >> 24) & 255;
        // 8-way max in fp16 (exact: max commutes with exact f16->f32 cvt)
        _Float16 g0 = s_u.g16[i0][o], g1 = s_u.g16[i1][o];
        _Float16 g2 = s_u.g16[i2][o], g3 = s_u.g16[i3_][o];
        _Float16 g4 = s_u.g16[i4][o], g5 = s_u.g16[i5][o];
        _Float16 g6 = s_u.g16[i6][o], g7 = s_u.g16[i7][o];
        _Float16 gm = hmax_(hmax_(hmax_(g0, g1), hmax_(g2, g3)),
                            hmax_(hmax_(g4, g5), hmax_(g6, g7)));
        acc = fmaxf(acc, (float)gm + base);   // base hoisted out of the k-max
    }
    __syncthreads();                       // g16 reads done -> reuse as red
    s_u.red[wv][o] = acc;
    __syncthreads();

    // ---- Phase G: cross-wave reduce, BN + leakyReLU + mask-max, store ----
    if (tid < CO) {
        float m = s_u.red[0][tid];
        #pragma unroll
        for (int i = 1; i < NW; ++i) m = fmaxf(m, s_u.red[i][tid]);
        float scale = bn_gamma[tid] / sqrtf(bn_var[tid] + 0.001f);
        float bias  = bn_beta[tid] - bn_mean[tid] * scale;
        float h = m * fabsf(scale) + bias;    // m tracks sgn*h_pre
        float a = (h > 0.f) ? h : 0.2f * h;   // leaky_relu
        if (nv < TPTS) a = fmaxf(a, 0.f);     // masked rows contribute 0
        out[v * CO + tid] = a;
    }
}

extern "C" void kernel_launch(void* const* d_in, const int* in_sizes, int n_in,
                              void* d_out, int out_size, void* d_ws, size_t ws_size,
                              hipStream_t stream) {
    const float* features = (const float*)d_in[0];
    const float* conv_w   = (const float*)d_in[1];
    const float* bn_gamma = (const float*)d_in[2];
    const float* bn_beta  = (const float*)d_in[3];
    const float* bn_mean  = (const float*)d_in[4];
    const float* bn_var   = (const float*)d_in[5];
    const int*   num_vox  = (const int*)d_in[6];
    const int*   coor     = (const int*)d_in[7];
    float* outp = (float*)d_out;
    const int V = in_sizes[6];   // 4096 voxels
    dgcnn_kernel<<<V, 512, 0, stream>>>(features, conv_w, bn_gamma, bn_beta,
                                        bn_mean, bn_var, num_vox, coor, outp);
}